// Round 2
// baseline (222.039 us; speedup 1.0000x reference)
//
#include <hip/hip_runtime.h>

constexpr int Bn = 64, T = 256, C = 384, H = 6, D = 64;
constexpr int BT = Bn * T;          // 16384
constexpr int NQKV = 3 * C;         // 1152
constexpr int WALL_ELEMS = NQKV * C; // 442368
constexpr int WP_ELEMS = C * C;      // 147456

using f32x4 = __attribute__((ext_vector_type(4))) float;
using fvec4 = __attribute__((ext_vector_type(4))) float;
using us8   = __attribute__((ext_vector_type(8))) unsigned short;
using bf8   = __attribute__((ext_vector_type(8))) __bf16;

__device__ __forceinline__ unsigned short f2bf(float f) {
  unsigned u = __builtin_bit_cast(unsigned, f);
  u += 0x7FFFu + ((u >> 16) & 1u);   // RNE; inputs are never NaN here
  return (unsigned short)(u >> 16);
}

__device__ __forceinline__ f32x4 mfma16(us8 a, us8 b, f32x4 c) {
  return __builtin_amdgcn_mfma_f32_16x16x32_bf16(
      __builtin_bit_cast(bf8, a), __builtin_bit_cast(bf8, b), c, 0, 0, 0);
}

// ---------------------------------------------------------------------------
// Pack weights: Wall_t[n][k]  n = proj*384 + h*64 + d, k = c  (N-major, bf16)
//               Wp_bf[n][k]   = Wp row-major (already N x K for Y*Wp^T)
// ---------------------------------------------------------------------------
__global__ __launch_bounds__(256) void k_prep(
    const float* __restrict__ Wq, const float* __restrict__ Wk,
    const float* __restrict__ Wv, const float* __restrict__ Wp,
    unsigned short* __restrict__ Wall, unsigned short* __restrict__ Wpb) {
  int i = blockIdx.x * 256 + threadIdx.x;
  if (i < WALL_ELEMS) {
    int n = i / C, c = i % C;
    int p = n / C;                 // 0=q 1=k 2=v
    int hd = n % C;
    int h = hd >> 6, d = hd & 63;
    const float* W = (p == 0) ? Wq : (p == 1) ? Wk : Wv;
    Wall[i] = f2bf(W[(h * C + c) * D + d]);
  } else {
    int j = i - WALL_ELEMS;
    if (j < WP_ELEMS) Wpb[j] = f2bf(Wp[j]);
  }
}

// ---------------------------------------------------------------------------
// QKV projection: [16384,384](f32,cast) x [1152,384]^T(bf16) -> QKV bf16
// tile 64x64, 4 waves, frags direct from global (B tile L2-resident)
// A-frag layout: lane holds A[l&15][8*(l>>4)+j]; B-frag: B[8*(l>>4)+j][l&15]
// ---------------------------------------------------------------------------
__global__ __launch_bounds__(256) void k_qkv(
    const float* __restrict__ x, const unsigned short* __restrict__ Wall,
    unsigned short* __restrict__ QKV) {
  const int nt = blockIdx.x, mt = blockIdx.y;
  const int w = threadIdx.x >> 6, lane = threadIdx.x & 63;
  const int lr = lane & 15, lg = lane >> 4;
  const int row = mt * 64 + w * 16 + lr;
  const int col0 = nt * 64;
  f32x4 acc[4];
#pragma unroll
  for (int nf = 0; nf < 4; ++nf) acc[nf] = (f32x4){0.f, 0.f, 0.f, 0.f};
  const float* xrow = x + (size_t)row * C;
#pragma unroll
  for (int kk = 0; kk < C / 32; ++kk) {
    const int k0 = kk * 32 + lg * 8;
    fvec4 x0 = *(const fvec4*)(xrow + k0);
    fvec4 x1 = *(const fvec4*)(xrow + k0 + 4);
    us8 a;
#pragma unroll
    for (int j = 0; j < 4; ++j) { a[j] = f2bf(x0[j]); a[4 + j] = f2bf(x1[j]); }
#pragma unroll
    for (int nf = 0; nf < 4; ++nf) {
      us8 bfrag = *(const us8*)(Wall + (size_t)(col0 + nf * 16 + lr) * C + k0);
      acc[nf] = mfma16(a, bfrag, acc[nf]);
    }
  }
  const int orow0 = mt * 64 + w * 16 + lg * 4;  // C/D: row=(l>>4)*4+r, col=l&15
#pragma unroll
  for (int nf = 0; nf < 4; ++nf)
#pragma unroll
    for (int r = 0; r < 4; ++r)
      QKV[(size_t)(orow0 + r) * NQKV + col0 + nf * 16 + lr] = f2bf(acc[nf][r]);
}

// ---------------------------------------------------------------------------
// Fused causal attention per (qtile, h, b). 8 waves, 16 q-rows each.
// K in LDS [256][72] (pad->free 2-way reads); V^T in LDS [64][264];
// P re-shaped via per-wave LDS chunk [16][40]. Block-uniform trip counts.
// ---------------------------------------------------------------------------
__global__ __launch_bounds__(512) void k_attn(
    const unsigned short* __restrict__ QKV, unsigned short* __restrict__ Y) {
  __shared__ unsigned short Klds[256][72];
  __shared__ unsigned short Vt[64][264];
  __shared__ unsigned short Pch[8][16][40];
  const int qt = blockIdx.x, h = blockIdx.y, b = blockIdx.z;
  const int t0 = qt * 128;
  const int kvlen = t0 + 128;                 // causal extent for this tile
  const int tid = threadIdx.x;
  const int w = tid >> 6, lane = tid & 63;
  const int lr = lane & 15, lg = lane >> 4;

  // ---- stage K rows and V transposed ----
  {
    const int c8 = (tid & 7) * 8;
    for (int r = tid >> 3; r < kvlen; r += 64) {
      const size_t base = (size_t)(b * T + r) * NQKV + h * D + c8;  // FIX: +c8
      us8 kv = *(const us8*)(QKV + base + C);
      *(us8*)&Klds[r][c8] = kv;
      us8 vv = *(const us8*)(QKV + base + 2 * C);
#pragma unroll
      for (int j = 0; j < 8; ++j) Vt[c8 + j][r] = vv[j];
    }
  }
  __syncthreads();

  // ---- Q fragments (A operand), rows t0 + w*16 + lr; lane k-offset lg*8 ----
  const size_t qbase = (size_t)(b * T + t0 + w * 16 + lr) * NQKV + h * D;
  const us8 aq0 = *(const us8*)(QKV + qbase + lg * 8);        // FIX: +lg*8
  const us8 aq1 = *(const us8*)(QKV + qbase + 32 + lg * 8);   // FIX: +lg*8

  const int nsf = kvlen / 16;                 // 8 or 16, block-uniform

  // ---- S = Q K^T (per wave: 16 x kvlen) ----
  f32x4 s[16];
#pragma unroll
  for (int sf = 0; sf < 16; ++sf) s[sf] = (f32x4){0.f, 0.f, 0.f, 0.f};
#pragma unroll
  for (int sf = 0; sf < 16; ++sf) {
    if (sf < nsf) {
      us8 kb0 = *(const us8*)&Klds[sf * 16 + lr][lg * 8];
      s[sf] = mfma16(aq0, kb0, s[sf]);
      us8 kb1 = *(const us8*)&Klds[sf * 16 + lr][32 + lg * 8];
      s[sf] = mfma16(aq1, kb1, s[sf]);
    }
  }

  // ---- scale + causal mask + row max (row = t0+w*16+lg*4+r, col = sf*16+lr)
  float mrow[4] = {-1e30f, -1e30f, -1e30f, -1e30f};
#pragma unroll
  for (int sf = 0; sf < 16; ++sf) {
    if (sf < nsf) {
#pragma unroll
      for (int r = 0; r < 4; ++r) {
        const int trow = t0 + w * 16 + lg * 4 + r;
        const int scol = sf * 16 + lr;
        float v = s[sf][r] * 0.125f;
        if (scol > trow) v = -1e30f;
        s[sf][r] = v;
        mrow[r] = fmaxf(mrow[r], v);
      }
    }
  }
#pragma unroll
  for (int dd = 1; dd < 16; dd <<= 1)
#pragma unroll
    for (int r = 0; r < 4; ++r)
      mrow[r] = fmaxf(mrow[r], __shfl_xor(mrow[r], dd, 64));

  // ---- exp + row sum (unnormalized P kept in regs) ----
  float psum[4] = {0.f, 0.f, 0.f, 0.f};
#pragma unroll
  for (int sf = 0; sf < 16; ++sf) {
    if (sf < nsf) {
#pragma unroll
      for (int r = 0; r < 4; ++r) {
        float p = __expf(s[sf][r] - mrow[r]);
        s[sf][r] = p;
        psum[r] += p;
      }
    }
  }
#pragma unroll
  for (int dd = 1; dd < 16; dd <<= 1)
#pragma unroll
    for (int r = 0; r < 4; ++r)
      psum[r] += __shfl_xor(psum[r], dd, 64);

  // ---- O = P V, 32-wide k-chunks via per-wave LDS round-trip ----
  f32x4 o[4];
#pragma unroll
  for (int nf = 0; nf < 4; ++nf) o[nf] = (f32x4){0.f, 0.f, 0.f, 0.f};
  const int nkk = nsf >> 1;
#pragma unroll
  for (int kk = 0; kk < 8; ++kk) {
    if (kk < nkk) {
#pragma unroll
      for (int half = 0; half < 2; ++half) {
        const int sf = kk * 2 + half;
#pragma unroll
        for (int r = 0; r < 4; ++r)
          Pch[w][lg * 4 + r][half * 16 + lr] = f2bf(s[sf][r]);
      }
      __builtin_amdgcn_wave_barrier();
      us8 pa = *(const us8*)&Pch[w][lr][lg * 8];  // A-frag of P
      __builtin_amdgcn_wave_barrier();
#pragma unroll
      for (int nf = 0; nf < 4; ++nf) {
        us8 bv = *(const us8*)&Vt[nf * 16 + lr][kk * 32 + lg * 8];
        o[nf] = mfma16(pa, bv, o[nf]);
      }
    }
  }

  // ---- normalize + store Y[b,t,h*64+d] bf16 ----
  float rs[4];
#pragma unroll
  for (int r = 0; r < 4; ++r) rs[r] = 1.0f / psum[r];
#pragma unroll
  for (int nf = 0; nf < 4; ++nf)
#pragma unroll
    for (int r = 0; r < 4; ++r) {
      const int trow = t0 + w * 16 + lg * 4 + r;
      Y[(size_t)(b * T + trow) * C + h * D + nf * 16 + lr] =
          f2bf(o[nf][r] * rs[r]);
    }
}

// ---------------------------------------------------------------------------
// Output projection: [16384,384](bf16) x Wp^T (Wp row-major = N x K) + bias
// ---------------------------------------------------------------------------
__global__ __launch_bounds__(256) void k_oproj(
    const unsigned short* __restrict__ Y, const unsigned short* __restrict__ Wpb,
    const float* __restrict__ bp, float* __restrict__ out) {
  const int nt = blockIdx.x, mt = blockIdx.y;
  const int w = threadIdx.x >> 6, lane = threadIdx.x & 63;
  const int lr = lane & 15, lg = lane >> 4;
  const int row = mt * 64 + w * 16 + lr;
  const int col0 = nt * 64;
  f32x4 acc[4];
#pragma unroll
  for (int nf = 0; nf < 4; ++nf) acc[nf] = (f32x4){0.f, 0.f, 0.f, 0.f};
  const unsigned short* yrow = Y + (size_t)row * C;
#pragma unroll
  for (int kk = 0; kk < C / 32; ++kk) {
    const int k0 = kk * 32 + lg * 8;
    us8 a = *(const us8*)(yrow + k0);
#pragma unroll
    for (int nf = 0; nf < 4; ++nf) {
      us8 bfrag = *(const us8*)(Wpb + (size_t)(col0 + nf * 16 + lr) * C + k0);
      acc[nf] = mfma16(a, bfrag, acc[nf]);
    }
  }
  const int orow0 = mt * 64 + w * 16 + lg * 4;
#pragma unroll
  for (int nf = 0; nf < 4; ++nf) {
    float bias = bp[col0 + nf * 16 + lr];
#pragma unroll
    for (int r = 0; r < 4; ++r)
      out[(size_t)(orow0 + r) * C + col0 + nf * 16 + lr] = acc[nf][r] + bias;
  }
}

extern "C" void kernel_launch(void* const* d_in, const int* in_sizes, int n_in,
                              void* d_out, int out_size, void* d_ws, size_t ws_size,
                              hipStream_t stream) {
  const float* x  = (const float*)d_in[0];
  const float* Wq = (const float*)d_in[1];
  const float* Wk = (const float*)d_in[2];
  const float* Wv = (const float*)d_in[3];
  const float* Wp = (const float*)d_in[4];
  const float* bp = (const float*)d_in[5];
  float* out = (float*)d_out;

  unsigned short* Wall = (unsigned short*)d_ws;             // 884,736 B
  unsigned short* Wpb  = Wall + WALL_ELEMS;                 // 294,912 B
  unsigned short* QKV  = Wpb + WP_ELEMS;                    // 37,748,736 B
  unsigned short* Yb   = QKV + (size_t)BT * NQKV;           // 12,582,912 B
  // total ws use: 51,511,296 B

  k_prep<<<(WALL_ELEMS + WP_ELEMS) / 256, 256, 0, stream>>>(Wq, Wk, Wv, Wp,
                                                            Wall, Wpb);
  k_qkv<<<dim3(NQKV / 64, BT / 64), 256, 0, stream>>>(x, Wall, QKV);
  k_attn<<<dim3(T / 128, H, Bn), 512, 0, stream>>>(QKV, Yb);
  k_oproj<<<dim3(C / 64, BT / 64), 256, 0, stream>>>(Yb, Wpb, bp, out);
}

// Round 3
// 83.459 us; speedup vs baseline: 2.6605x; 2.6605x over previous
//
#include <hip/hip_runtime.h>

constexpr int Bn = 64, T = 256, C = 384, H = 6, D = 64;
constexpr int BT = Bn * T;          // 16384
constexpr int NQKV = 3 * C;         // 1152
constexpr int WALL_ELEMS = NQKV * C; // 442368
constexpr int WP_ELEMS = C * C;      // 147456

using f32x4 = __attribute__((ext_vector_type(4))) float;
using fvec4 = __attribute__((ext_vector_type(4))) float;
using us8   = __attribute__((ext_vector_type(8))) unsigned short;
using bf8   = __attribute__((ext_vector_type(8))) __bf16;

__device__ __forceinline__ unsigned short f2bf(float f) {
  unsigned u = __builtin_bit_cast(unsigned, f);
  u += 0x7FFFu + ((u >> 16) & 1u);   // RNE; inputs are never NaN here
  return (unsigned short)(u >> 16);
}

__device__ __forceinline__ f32x4 mfma16(us8 a, us8 b, f32x4 c) {
  return __builtin_amdgcn_mfma_f32_16x16x32_bf16(
      __builtin_bit_cast(bf8, a), __builtin_bit_cast(bf8, b), c, 0, 0, 0);
}

// ---------------------------------------------------------------------------
// Pack weights: Wall_t[n][k]  n = proj*384 + h*64 + d, k = c  (N-major, bf16)
//               Wp_bf[n][k]   = Wp row-major (already N x K for Y*Wp^T)
// ---------------------------------------------------------------------------
__global__ __launch_bounds__(256) void k_prep(
    const float* __restrict__ Wq, const float* __restrict__ Wk,
    const float* __restrict__ Wv, const float* __restrict__ Wp,
    unsigned short* __restrict__ Wall, unsigned short* __restrict__ Wpb) {
  int i = blockIdx.x * 256 + threadIdx.x;
  if (i < WALL_ELEMS) {
    int n = i / C, c = i % C;
    int p = n / C;                 // 0=q 1=k 2=v
    int hd = n % C;
    int h = hd >> 6, d = hd & 63;
    const float* W = (p == 0) ? Wq : (p == 1) ? Wk : Wv;
    Wall[i] = f2bf(W[(h * C + c) * D + d]);
  } else {
    int j = i - WALL_ELEMS;
    if (j < WP_ELEMS) Wpb[j] = f2bf(Wp[j]);
  }
}

// ---------------------------------------------------------------------------
// Cast x f32 -> bf16 (read once; GEMM then re-reads bf16 from L2/L3)
// ---------------------------------------------------------------------------
__global__ __launch_bounds__(256) void k_xcast(
    const float* __restrict__ x, unsigned short* __restrict__ Xb) {
  const int i = (blockIdx.x * 256 + threadIdx.x) * 8;
  fvec4 a = *(const fvec4*)(x + i);
  fvec4 b = *(const fvec4*)(x + i + 4);
  us8 o;
#pragma unroll
  for (int j = 0; j < 4; ++j) { o[j] = f2bf(a[j]); o[4 + j] = f2bf(b[j]); }
  *(us8*)(Xb + i) = o;
}

// ---------------------------------------------------------------------------
// Tiled GEMM: A[M][384] bf16  x  Bm[N][384] bf16 (N-major)  -> O[M][Nld]
// 128x128 tile, BK=64, 4 waves (each 64x64 = 4x4 frags), double-buffered LDS,
// global_load_lds width-16 staging with XOR-swizzled SOURCE (linear LDS dest,
// m173 pattern): LDS chunk c of row r holds global chunk c ^ (r&7); frag
// ds_read_b128 applies the same XOR -> conflict-free.
// ---------------------------------------------------------------------------
__device__ __forceinline__ void stage_tile(
    const unsigned short* __restrict__ g, unsigned short* l,
    int row0g, int k0, int tr, int tc, int w) {
#pragma unroll
  for (int s = 0; s < 4; ++s) {
    const int row = s * 32 + tr;
    const int sc = (tc ^ (row & 7)) * 8;
    const unsigned short* ga = g + (size_t)(row0g + row) * C + k0 + sc;
    unsigned short* la = l + (s * 32 + w * 8) * 64;  // wave-uniform base
    __builtin_amdgcn_global_load_lds(
        (const __attribute__((address_space(1))) unsigned int*)ga,
        (__attribute__((address_space(3))) unsigned int*)la, 16, 0, 0);
  }
}

template <bool BF16_OUT>
__global__ __launch_bounds__(256) void k_gemm(
    const unsigned short* __restrict__ A,   // [16384][384]
    const unsigned short* __restrict__ Bm,  // [N][384]
    const float* __restrict__ bias,         // used when !BF16_OUT
    unsigned short* __restrict__ Obf, float* __restrict__ Of, int Nld) {
  constexpr int BK = 64, NT = C / BK;       // 6 K-steps
  __shared__ unsigned short Al[2][128 * BK];
  __shared__ unsigned short Bl[2][128 * BK];
  const int tid = threadIdx.x;
  const int w = tid >> 6, lane = tid & 63;
  const int lr = lane & 15, lg = lane >> 4;
  const int m0 = blockIdx.y * 128, n0 = blockIdx.x * 128;
  const int wm = (w >> 1) * 64, wn = (w & 1) * 64;
  const int tr = tid >> 3, tc = tid & 7;    // staging row/chunk

  f32x4 acc[4][4];
#pragma unroll
  for (int i = 0; i < 4; ++i)
#pragma unroll
    for (int j = 0; j < 4; ++j) acc[i][j] = (f32x4){0.f, 0.f, 0.f, 0.f};

  stage_tile(A, &Al[0][0], m0, 0, tr, tc, w);
  stage_tile(Bm, &Bl[0][0], n0, 0, tr, tc, w);
  __syncthreads();

  int cur = 0;
  for (int t = 0; t < NT; ++t) {
    if (t + 1 < NT) {
      stage_tile(A, &Al[cur ^ 1][0], m0, (t + 1) * BK, tr, tc, w);
      stage_tile(Bm, &Bl[cur ^ 1][0], n0, (t + 1) * BK, tr, tc, w);
    }
#pragma unroll
    for (int kc = 0; kc < 2; ++kc) {
      us8 af[4], bfr[4];
#pragma unroll
      for (int i = 0; i < 4; ++i) {
        const int ra = wm + i * 16 + lr;
        af[i] = *(const us8*)&Al[cur][ra * 64 + (((kc * 4 + lg) ^ (ra & 7)) * 8)];
        const int rb = wn + i * 16 + lr;
        bfr[i] = *(const us8*)&Bl[cur][rb * 64 + (((kc * 4 + lg) ^ (rb & 7)) * 8)];
      }
#pragma unroll
      for (int i = 0; i < 4; ++i)
#pragma unroll
        for (int j = 0; j < 4; ++j)
          acc[i][j] = mfma16(af[i], bfr[j], acc[i][j]);
    }
    __syncthreads();   // drains vmcnt (staging) + lgkmcnt before buffer swap
    cur ^= 1;
  }

  // epilogue: C/D frag row=(lane>>4)*4+r, col=lane&15
#pragma unroll
  for (int i = 0; i < 4; ++i)
#pragma unroll
    for (int j = 0; j < 4; ++j) {
      const int col = n0 + wn + j * 16 + lr;
      float bv = BF16_OUT ? 0.f : bias[col];
#pragma unroll
      for (int r = 0; r < 4; ++r) {
        const size_t row = m0 + wm + i * 16 + lg * 4 + r;
        if (BF16_OUT)
          Obf[row * Nld + col] = f2bf(acc[i][j][r]);
        else
          Of[row * Nld + col] = acc[i][j][r] + bv;
      }
    }
}

// ---------------------------------------------------------------------------
// Fused causal attention per (qtile, h, b). 8 waves, 16 q-rows each.
// K in LDS [256][72] (pad->free 2-way reads); V^T in LDS [64][264];
// P re-shaped via per-wave LDS chunk [16][40]. Block-uniform trip counts.
// ---------------------------------------------------------------------------
__global__ __launch_bounds__(512) void k_attn(
    const unsigned short* __restrict__ QKV, unsigned short* __restrict__ Y) {
  __shared__ unsigned short Klds[256][72];
  __shared__ unsigned short Vt[64][264];
  __shared__ unsigned short Pch[8][16][40];
  const int qt = blockIdx.x, h = blockIdx.y, b = blockIdx.z;
  const int t0 = qt * 128;
  const int kvlen = t0 + 128;                 // causal extent for this tile
  const int tid = threadIdx.x;
  const int w = tid >> 6, lane = tid & 63;
  const int lr = lane & 15, lg = lane >> 4;

  // ---- stage K rows and V transposed ----
  {
    const int c8 = (tid & 7) * 8;
    for (int r = tid >> 3; r < kvlen; r += 64) {
      const size_t base = (size_t)(b * T + r) * NQKV + h * D + c8;
      us8 kv = *(const us8*)(QKV + base + C);
      *(us8*)&Klds[r][c8] = kv;
      us8 vv = *(const us8*)(QKV + base + 2 * C);
#pragma unroll
      for (int j = 0; j < 8; ++j) Vt[c8 + j][r] = vv[j];
    }
  }
  __syncthreads();

  // ---- Q fragments (A operand), rows t0 + w*16 + lr; lane k-offset lg*8 ----
  const size_t qbase = (size_t)(b * T + t0 + w * 16 + lr) * NQKV + h * D;
  const us8 aq0 = *(const us8*)(QKV + qbase + lg * 8);
  const us8 aq1 = *(const us8*)(QKV + qbase + 32 + lg * 8);

  const int nsf = kvlen / 16;                 // 8 or 16, block-uniform

  // ---- S = Q K^T (per wave: 16 x kvlen) ----
  f32x4 s[16];
#pragma unroll
  for (int sf = 0; sf < 16; ++sf) s[sf] = (f32x4){0.f, 0.f, 0.f, 0.f};
#pragma unroll
  for (int sf = 0; sf < 16; ++sf) {
    if (sf < nsf) {
      us8 kb0 = *(const us8*)&Klds[sf * 16 + lr][lg * 8];
      s[sf] = mfma16(aq0, kb0, s[sf]);
      us8 kb1 = *(const us8*)&Klds[sf * 16 + lr][32 + lg * 8];
      s[sf] = mfma16(aq1, kb1, s[sf]);
    }
  }

  // ---- scale + causal mask + row max (row = t0+w*16+lg*4+r, col = sf*16+lr)
  float mrow[4] = {-1e30f, -1e30f, -1e30f, -1e30f};
#pragma unroll
  for (int sf = 0; sf < 16; ++sf) {
    if (sf < nsf) {
#pragma unroll
      for (int r = 0; r < 4; ++r) {
        const int trow = t0 + w * 16 + lg * 4 + r;
        const int scol = sf * 16 + lr;
        float v = s[sf][r] * 0.125f;
        if (scol > trow) v = -1e30f;
        s[sf][r] = v;
        mrow[r] = fmaxf(mrow[r], v);
      }
    }
  }
#pragma unroll
  for (int dd = 1; dd < 16; dd <<= 1)
#pragma unroll
    for (int r = 0; r < 4; ++r)
      mrow[r] = fmaxf(mrow[r], __shfl_xor(mrow[r], dd, 64));

  // ---- exp + row sum (unnormalized P kept in regs) ----
  float psum[4] = {0.f, 0.f, 0.f, 0.f};
#pragma unroll
  for (int sf = 0; sf < 16; ++sf) {
    if (sf < nsf) {
#pragma unroll
      for (int r = 0; r < 4; ++r) {
        float p = __expf(s[sf][r] - mrow[r]);
        s[sf][r] = p;
        psum[r] += p;
      }
    }
  }
#pragma unroll
  for (int dd = 1; dd < 16; dd <<= 1)
#pragma unroll
    for (int r = 0; r < 4; ++r)
      psum[r] += __shfl_xor(psum[r], dd, 64);

  // ---- O = P V, 32-wide k-chunks via per-wave LDS round-trip ----
  f32x4 o[4];
#pragma unroll
  for (int nf = 0; nf < 4; ++nf) o[nf] = (f32x4){0.f, 0.f, 0.f, 0.f};
  const int nkk = nsf >> 1;
#pragma unroll
  for (int kk = 0; kk < 8; ++kk) {
    if (kk < nkk) {
#pragma unroll
      for (int half = 0; half < 2; ++half) {
        const int sf = kk * 2 + half;
#pragma unroll
        for (int r = 0; r < 4; ++r)
          Pch[w][lg * 4 + r][half * 16 + lr] = f2bf(s[sf][r]);
      }
      __builtin_amdgcn_wave_barrier();
      us8 pa = *(const us8*)&Pch[w][lr][lg * 8];  // A-frag of P
      __builtin_amdgcn_wave_barrier();
#pragma unroll
      for (int nf = 0; nf < 4; ++nf) {
        us8 bv = *(const us8*)&Vt[nf * 16 + lr][kk * 32 + lg * 8];
        o[nf] = mfma16(pa, bv, o[nf]);
      }
    }
  }

  // ---- normalize + store Y[b,t,h*64+d] bf16 ----
  float rs[4];
#pragma unroll
  for (int r = 0; r < 4; ++r) rs[r] = 1.0f / psum[r];
#pragma unroll
  for (int nf = 0; nf < 4; ++nf)
#pragma unroll
    for (int r = 0; r < 4; ++r) {
      const int trow = t0 + w * 16 + lg * 4 + r;
      Y[(size_t)(b * T + trow) * C + h * D + nf * 16 + lr] =
          f2bf(o[nf][r] * rs[r]);
    }
}

extern "C" void kernel_launch(void* const* d_in, const int* in_sizes, int n_in,
                              void* d_out, int out_size, void* d_ws, size_t ws_size,
                              hipStream_t stream) {
  const float* x  = (const float*)d_in[0];
  const float* Wq = (const float*)d_in[1];
  const float* Wk = (const float*)d_in[2];
  const float* Wv = (const float*)d_in[3];
  const float* Wp = (const float*)d_in[4];
  const float* bp = (const float*)d_in[5];
  float* out = (float*)d_out;

  unsigned short* Wall = (unsigned short*)d_ws;             // 884,736 B
  unsigned short* Wpb  = Wall + WALL_ELEMS;                 // 294,912 B
  unsigned short* QKV  = Wpb + WP_ELEMS;                    // 37,748,736 B
  unsigned short* Yb   = QKV + (size_t)BT * NQKV;           // 12,582,912 B
  unsigned short* Xb   = Yb;  // alias: Xb only live before k_attn writes Yb
  // total ws use: 51,511,296 B (unchanged)

  k_prep<<<(WALL_ELEMS + WP_ELEMS) / 256, 256, 0, stream>>>(Wq, Wk, Wv, Wp,
                                                            Wall, Wpb);
  k_xcast<<<BT * C / (256 * 8), 256, 0, stream>>>(x, Xb);
  k_gemm<true><<<dim3(NQKV / 128, BT / 128), 256, 0, stream>>>(
      Xb, Wall, nullptr, QKV, nullptr, NQKV);
  k_attn<<<dim3(T / 128, H, Bn), 512, 0, stream>>>(QKV, Yb);
  k_gemm<false><<<dim3(C / 128, BT / 128), 256, 0, stream>>>(
      Yb, Wpb, bp, nullptr, out, C);
}

// Round 4
// 72.794 us; speedup vs baseline: 3.0502x; 1.1465x over previous
//
#include <hip/hip_runtime.h>

constexpr int Bn = 64, T = 256, C = 384, H = 6, D = 64;
constexpr int BT = Bn * T;          // 16384
constexpr int NQKV = 3 * C;         // 1152
constexpr int WALL_ELEMS = NQKV * C; // 442368
constexpr int WP_ELEMS = C * C;      // 147456

using f32x4 = __attribute__((ext_vector_type(4))) float;
using fvec4 = __attribute__((ext_vector_type(4))) float;
using us8   = __attribute__((ext_vector_type(8))) unsigned short;
using bf8   = __attribute__((ext_vector_type(8))) __bf16;

__device__ __forceinline__ unsigned short f2bf(float f) {
  unsigned u = __builtin_bit_cast(unsigned, f);
  u += 0x7FFFu + ((u >> 16) & 1u);   // RNE; inputs are never NaN here
  return (unsigned short)(u >> 16);
}

__device__ __forceinline__ f32x4 mfma16(us8 a, us8 b, f32x4 c) {
  return __builtin_amdgcn_mfma_f32_16x16x32_bf16(
      __builtin_bit_cast(bf8, a), __builtin_bit_cast(bf8, b), c, 0, 0, 0);
}

// ---------------------------------------------------------------------------
// Pack Wq/Wk/Wv -> Wall_t[n][c] (n = p*384+h*64+d) via LDS transpose tiles.
// Reads coalesced (lane = d, 256B segments), writes coalesced us8.
// grid: (3p * 6h * 6ct) = 108 blocks x 256 thr
// ---------------------------------------------------------------------------
__global__ __launch_bounds__(256) void k_prep(
    const float* __restrict__ Wq, const float* __restrict__ Wk,
    const float* __restrict__ Wv, unsigned short* __restrict__ Wall) {
  __shared__ unsigned short t[64][71];   // [c_loc][d], odd-ish stride
  const int bid = blockIdx.x;
  const int ct = bid % 6, ph = bid / 6;
  const int h = ph % 6, p = ph / 6;
  const float* W = (p == 0) ? Wq : (p == 1) ? Wk : Wv;
  const int c0 = ct * 64;
  const int tid = threadIdx.x;
  const int d = tid & 63, cq = tid >> 6;
#pragma unroll
  for (int s = 0; s < 16; ++s) {
    const int c_loc = cq * 16 + s;
    t[c_loc][d] = f2bf(W[(size_t)(h * C + c0 + c_loc) * D + d]);
  }
  __syncthreads();
  const int d_loc = tid >> 2, ch = tid & 3;
#pragma unroll
  for (int it = 0; it < 2; ++it) {
    const int cc = (ch + it * 4) * 8;
    us8 o;
#pragma unroll
    for (int j = 0; j < 8; ++j) o[j] = t[cc + j][d_loc];
    *(us8*)&Wall[(size_t)(p * C + h * D + d_loc) * C + c0 + cc] = o;
  }
}

// ---------------------------------------------------------------------------
// Cast x f32 -> bf16 (and Wp -> Wpb in the grid tail)
// ---------------------------------------------------------------------------
__global__ __launch_bounds__(256) void k_xcast(
    const float* __restrict__ x, unsigned short* __restrict__ Xb,
    const float* __restrict__ Wp, unsigned short* __restrict__ Wpb) {
  const int i = (blockIdx.x * 256 + threadIdx.x) * 8;
  const float* src;
  unsigned short* dst;
  int off;
  if (i < BT * C) { src = x; dst = Xb; off = i; }
  else { src = Wp; dst = Wpb; off = i - BT * C; }
  fvec4 a = *(const fvec4*)(src + off);
  fvec4 b = *(const fvec4*)(src + off + 4);
  us8 o;
#pragma unroll
  for (int j = 0; j < 4; ++j) { o[j] = f2bf(a[j]); o[4 + j] = f2bf(b[j]); }
  *(us8*)(dst + off) = o;
}

// ---------------------------------------------------------------------------
// Tiled GEMM: A[M][384] bf16  x  Bm[N][384] bf16 (N-major)  -> O[M][Nld]
// 128x128 tile, BK=64, 4 waves, double-buffered LDS, global_load_lds w=16,
// XOR-swizzled SOURCE (linear LDS dest). 1D grid + bijective XCD swizzle:
// each XCD chunk = 16 m-panels x all n-tiles (B + A-panels L2-resident).
// ---------------------------------------------------------------------------
__device__ __forceinline__ void stage_tile(
    const unsigned short* __restrict__ g, unsigned short* l,
    int row0g, int k0, int tr, int tc, int w) {
#pragma unroll
  for (int s = 0; s < 4; ++s) {
    const int row = s * 32 + tr;
    const int sc = (tc ^ (row & 7)) * 8;
    const unsigned short* ga = g + (size_t)(row0g + row) * C + k0 + sc;
    unsigned short* la = l + (s * 32 + w * 8) * 64;  // wave-uniform base
    __builtin_amdgcn_global_load_lds(
        (const __attribute__((address_space(1))) unsigned int*)ga,
        (__attribute__((address_space(3))) unsigned int*)la, 16, 0, 0);
  }
}

template <bool BF16_OUT>
__global__ __launch_bounds__(256) void k_gemm(
    const unsigned short* __restrict__ A,   // [16384][384]
    const unsigned short* __restrict__ Bm,  // [N][384]
    const float* __restrict__ bias,         // used when !BF16_OUT
    unsigned short* __restrict__ Obf, float* __restrict__ Of,
    int Nld, int nwgn) {
  constexpr int BK = 64, NT = C / BK;       // 6 K-steps
  __shared__ unsigned short Al[2][128 * BK];
  __shared__ unsigned short Bl[2][128 * BK];
  const int nwg = gridDim.x;
  const int bid = blockIdx.x;
  const int lin = (bid & 7) * (nwg >> 3) + (bid >> 3);  // bijective (nwg%8==0)
  const int m0 = (lin / nwgn) * 128, n0 = (lin % nwgn) * 128;
  const int tid = threadIdx.x;
  const int w = tid >> 6, lane = tid & 63;
  const int lr = lane & 15, lg = lane >> 4;
  const int wm = (w >> 1) * 64, wn = (w & 1) * 64;
  const int tr = tid >> 3, tc = tid & 7;    // staging row/chunk

  f32x4 acc[4][4];
#pragma unroll
  for (int i = 0; i < 4; ++i)
#pragma unroll
    for (int j = 0; j < 4; ++j) acc[i][j] = (f32x4){0.f, 0.f, 0.f, 0.f};

  stage_tile(A, &Al[0][0], m0, 0, tr, tc, w);
  stage_tile(Bm, &Bl[0][0], n0, 0, tr, tc, w);
  __syncthreads();

  int cur = 0;
  for (int t = 0; t < NT; ++t) {
    if (t + 1 < NT) {
      stage_tile(A, &Al[cur ^ 1][0], m0, (t + 1) * BK, tr, tc, w);
      stage_tile(Bm, &Bl[cur ^ 1][0], n0, (t + 1) * BK, tr, tc, w);
    }
#pragma unroll
    for (int kc = 0; kc < 2; ++kc) {
      us8 af[4], bfr[4];
#pragma unroll
      for (int i = 0; i < 4; ++i) {
        const int ra = wm + i * 16 + lr;
        af[i] = *(const us8*)&Al[cur][ra * 64 + (((kc * 4 + lg) ^ (ra & 7)) * 8)];
        const int rb = wn + i * 16 + lr;
        bfr[i] = *(const us8*)&Bl[cur][rb * 64 + (((kc * 4 + lg) ^ (rb & 7)) * 8)];
      }
#pragma unroll
      for (int i = 0; i < 4; ++i)
#pragma unroll
        for (int j = 0; j < 4; ++j)
          acc[i][j] = mfma16(af[i], bfr[j], acc[i][j]);
    }
    __syncthreads();   // drains vmcnt (staging) + lgkmcnt before buffer swap
    cur ^= 1;
  }

  // epilogue: C/D frag row=(lane>>4)*4+r, col=lane&15
#pragma unroll
  for (int i = 0; i < 4; ++i)
#pragma unroll
    for (int j = 0; j < 4; ++j) {
      const int col = n0 + wn + j * 16 + lr;
      float bv = BF16_OUT ? 0.f : bias[col];
#pragma unroll
      for (int r = 0; r < 4; ++r) {
        const size_t row = m0 + wm + i * 16 + lg * 4 + r;
        if (BF16_OUT)
          Obf[row * Nld + col] = f2bf(acc[i][j][r]);
        else
          Of[row * Nld + col] = acc[i][j][r] + bv;
      }
    }
}

// ---------------------------------------------------------------------------
// Fused causal attention. 1D grid (768, XCD-swizzled), 8 waves, 16 q-rows/wave.
// K in LDS [256][72]; V^T in LDS [64][264]; P via per-wave XOR-swizzled chunk.
// LDS total 78.8KB -> 2 blocks/CU.
// ---------------------------------------------------------------------------
__global__ __launch_bounds__(512, 4) void k_attn(
    const unsigned short* __restrict__ QKV, unsigned short* __restrict__ Y) {
  __shared__ unsigned short Klds[256][72];
  __shared__ unsigned short Vt[64][264];
  __shared__ unsigned short Pch[8][16][32];
  const int bid = blockIdx.x;
  const int lin = (bid & 7) * 96 + (bid >> 3);   // bijective: 768 % 8 == 0
  const int b = lin / 12, rr = lin % 12;
  const int h = rr >> 1, qt = rr & 1;
  const int t0 = qt * 128;
  const int kvlen = t0 + 128;                 // causal extent for this tile
  const int tid = threadIdx.x;
  const int w = tid >> 6, lane = tid & 63;
  const int lr = lane & 15, lg = lane >> 4;

  // ---- stage K rows and V transposed ----
  {
    const int c8 = (tid & 7) * 8;
    for (int r = tid >> 3; r < kvlen; r += 64) {
      const size_t base = (size_t)(b * T + r) * NQKV + h * D + c8;
      us8 kv = *(const us8*)(QKV + base + C);
      *(us8*)&Klds[r][c8] = kv;
      us8 vv = *(const us8*)(QKV + base + 2 * C);
#pragma unroll
      for (int j = 0; j < 8; ++j) Vt[c8 + j][r] = vv[j];
    }
  }
  __syncthreads();

  // ---- Q fragments (A operand), rows t0 + w*16 + lr; lane k-offset lg*8 ----
  const size_t qbase = (size_t)(b * T + t0 + w * 16 + lr) * NQKV + h * D;
  const us8 aq0 = *(const us8*)(QKV + qbase + lg * 8);
  const us8 aq1 = *(const us8*)(QKV + qbase + 32 + lg * 8);

  const int nsf = kvlen / 16;                 // 8 or 16, block-uniform

  // ---- S = Q K^T (per wave: 16 x kvlen) ----
  f32x4 s[16];
#pragma unroll
  for (int sf = 0; sf < 16; ++sf) s[sf] = (f32x4){0.f, 0.f, 0.f, 0.f};
#pragma unroll
  for (int sf = 0; sf < 16; ++sf) {
    if (sf < nsf) {
      us8 kb0 = *(const us8*)&Klds[sf * 16 + lr][lg * 8];
      s[sf] = mfma16(aq0, kb0, s[sf]);
      us8 kb1 = *(const us8*)&Klds[sf * 16 + lr][32 + lg * 8];
      s[sf] = mfma16(aq1, kb1, s[sf]);
    }
  }

  // ---- scale + causal mask + row max (row = t0+w*16+lg*4+r, col = sf*16+lr)
  float mrow[4] = {-1e30f, -1e30f, -1e30f, -1e30f};
#pragma unroll
  for (int sf = 0; sf < 16; ++sf) {
    if (sf < nsf) {
#pragma unroll
      for (int r = 0; r < 4; ++r) {
        const int trow = t0 + w * 16 + lg * 4 + r;
        const int scol = sf * 16 + lr;
        float v = s[sf][r] * 0.125f;
        if (scol > trow) v = -1e30f;
        s[sf][r] = v;
        mrow[r] = fmaxf(mrow[r], v);
      }
    }
  }
#pragma unroll
  for (int dd = 1; dd < 16; dd <<= 1)
#pragma unroll
    for (int r = 0; r < 4; ++r)
      mrow[r] = fmaxf(mrow[r], __shfl_xor(mrow[r], dd, 64));

  // ---- exp + row sum (unnormalized P kept in regs) ----
  float psum[4] = {0.f, 0.f, 0.f, 0.f};
#pragma unroll
  for (int sf = 0; sf < 16; ++sf) {
    if (sf < nsf) {
#pragma unroll
      for (int r = 0; r < 4; ++r) {
        float p = __expf(s[sf][r] - mrow[r]);
        s[sf][r] = p;
        psum[r] += p;
      }
    }
  }
#pragma unroll
  for (int dd = 1; dd < 16; dd <<= 1)
#pragma unroll
    for (int r = 0; r < 4; ++r)
      psum[r] += __shfl_xor(psum[r], dd, 64);

  // ---- O = P V, 32-wide k-chunks via per-wave swizzled LDS round-trip ----
  f32x4 o[4];
#pragma unroll
  for (int nf = 0; nf < 4; ++nf) o[nf] = (f32x4){0.f, 0.f, 0.f, 0.f};
  const int nkk = nsf >> 1;
#pragma unroll
  for (int kk = 0; kk < 8; ++kk) {
    if (kk < nkk) {
#pragma unroll
      for (int half = 0; half < 2; ++half) {
        const int sf = kk * 2 + half;
        const int row = lg * 4;
#pragma unroll
        for (int r = 0; r < 4; ++r) {
          const int cch = (half * 2 + (lr >> 3)) ^ ((row + r) & 3);
          Pch[w][row + r][cch * 8 + (lr & 7)] = f2bf(s[sf][r]);
        }
      }
      __builtin_amdgcn_wave_barrier();
      us8 pa = *(const us8*)&Pch[w][lr][(lg ^ (lr & 3)) * 8];  // A-frag of P
      __builtin_amdgcn_wave_barrier();
#pragma unroll
      for (int nf = 0; nf < 4; ++nf) {
        us8 bv = *(const us8*)&Vt[nf * 16 + lr][kk * 32 + lg * 8];
        o[nf] = mfma16(pa, bv, o[nf]);
      }
    }
  }

  // ---- normalize + store Y[b,t,h*64+d] bf16 ----
  float rs[4];
#pragma unroll
  for (int r = 0; r < 4; ++r) rs[r] = 1.0f / psum[r];
#pragma unroll
  for (int nf = 0; nf < 4; ++nf)
#pragma unroll
    for (int r = 0; r < 4; ++r) {
      const int trow = t0 + w * 16 + lg * 4 + r;
      Y[(size_t)(b * T + trow) * C + h * D + nf * 16 + lr] =
          f2bf(o[nf][r] * rs[r]);
    }
}

extern "C" void kernel_launch(void* const* d_in, const int* in_sizes, int n_in,
                              void* d_out, int out_size, void* d_ws, size_t ws_size,
                              hipStream_t stream) {
  const float* x  = (const float*)d_in[0];
  const float* Wq = (const float*)d_in[1];
  const float* Wk = (const float*)d_in[2];
  const float* Wv = (const float*)d_in[3];
  const float* Wp = (const float*)d_in[4];
  const float* bp = (const float*)d_in[5];
  float* out = (float*)d_out;

  unsigned short* Wall = (unsigned short*)d_ws;             // 884,736 B
  unsigned short* Wpb  = Wall + WALL_ELEMS;                 // 294,912 B
  unsigned short* QKV  = Wpb + WP_ELEMS;                    // 37,748,736 B
  unsigned short* Yb   = QKV + (size_t)BT * NQKV;           // 12,582,912 B
  unsigned short* Xb   = Yb;  // alias: Xb only live before k_attn writes Yb

  k_prep<<<108, 256, 0, stream>>>(Wq, Wk, Wv, Wall);
  k_xcast<<<(BT * C + WP_ELEMS) / (256 * 8), 256, 0, stream>>>(x, Xb, Wp, Wpb);
  k_gemm<true><<<NQKV / 128 * (BT / 128), 256, 0, stream>>>(
      Xb, Wall, nullptr, QKV, nullptr, NQKV, NQKV / 128);
  k_attn<<<T / 128 * H * Bn, 512, 0, stream>>>(QKV, Yb);
  k_gemm<false><<<C / 128 * (BT / 128), 256, 0, stream>>>(
      Yb, Wpb, bp, nullptr, out, C, C / 128);
}